// Round 1
// baseline (1932.240 us; speedup 1.0000x reference)
//
#include <hip/hip_runtime.h>
#include <stdint.h>

#define NN 8192
#define NE 65536
#define ET (NE + NN)
#define F_IN   3247
#define F_IN_P 3264
#define F_EXP   7993
#define F_EXP_P 8000

typedef __attribute__((ext_vector_type(8))) short bf16x8;
typedef __attribute__((ext_vector_type(4))) float f32x4;

typedef const __attribute__((address_space(1))) void gvoid_t;
typedef __attribute__((address_space(3))) void lvoid_t;

__device__ __forceinline__ float bf2f(uint16_t u) {
  union { uint32_t i; float f; } v; v.i = ((uint32_t)u) << 16; return v.f;
}
__device__ __forceinline__ uint16_t f2bf(float f) {
  union { float f; uint32_t i; } v; v.f = f;
  uint32_t r = v.i + 0x7fffu + ((v.i >> 16) & 1u);  // RNE
  return (uint16_t)(r >> 16);
}

__device__ __forceinline__ void gld_lds16(const void* g, void* l) {
  __builtin_amdgcn_global_load_lds((gvoid_t*)g, (lvoid_t*)l, 16, 0, 0);
}

// ---------------------------------------------------------------- GEMM (m97 structure)
// C[M][ldc](bf16) = A[M][Kp](bf16,row-major) x Bt[Np][Kp](bf16,row-major)^T + bias (+relu)
// M%128==0, Np%128==0 (grid covers exactly), Kp%32==0.
__global__ __launch_bounds__(256)
void gemm_bt(const uint16_t* __restrict__ A, const uint16_t* __restrict__ Bt,
             const float* __restrict__ bias, int biasN, int relu,
             uint16_t* __restrict__ C, int Kp, int ldc)
{
  __shared__ uint16_t As[128 * 32];   // 8 KB, row-major [128][32]
  __shared__ uint16_t Bs[128 * 32];
  const int tid  = threadIdx.x;
  const int wave = tid >> 6, lane = tid & 63;
  const int brow = blockIdx.x * 128, bcol = blockIdx.y * 128;
  const int wr = wave >> 1, wc = wave & 1;
  const int fr = lane & 15, g = lane >> 4;

  f32x4 acc[4][4];
#pragma unroll
  for (int m = 0; m < 4; ++m)
#pragma unroll
    for (int n = 0; n < 4; ++n) acc[m][n] = (f32x4){0.f, 0.f, 0.f, 0.f};

  // staging geometry: chunk c = p*256 + tid covers row c>>2, k-offset (c&3)*8
  const int rA = tid >> 2;
  const int kc = (tid & 3) * 8;
  const uint16_t* aptr = A  + (size_t)(brow + rA) * Kp + kc;
  const uint16_t* bptr = Bt + (size_t)(bcol + rA) * Kp + kc;
  char* ldsA = (char*)As + wave * 1024;   // wave-uniform base; HW adds lane*16
  char* ldsB = (char*)Bs + wave * 1024;
  const size_t rowskip = (size_t)64 * Kp;

  const int nk = Kp >> 5;
  for (int kt = 0; kt < nk; ++kt) {
    __syncthreads();
    gld_lds16(aptr,           ldsA);
    gld_lds16(aptr + rowskip, ldsA + 4096);
    gld_lds16(bptr,           ldsB);
    gld_lds16(bptr + rowskip, ldsB + 4096);
    aptr += 32; bptr += 32;
    __syncthreads();

    bf16x8 af[4], bfr[4];
#pragma unroll
    for (int m = 0; m < 4; ++m)
      af[m] = *(const bf16x8*)&As[(wr * 64 + m * 16 + fr) * 32 + g * 8];
#pragma unroll
    for (int n = 0; n < 4; ++n)
      bfr[n] = *(const bf16x8*)&Bs[(wc * 64 + n * 16 + fr) * 32 + g * 8];
#pragma unroll
    for (int m = 0; m < 4; ++m)
#pragma unroll
      for (int n = 0; n < 4; ++n)
        acc[m][n] = __builtin_amdgcn_mfma_f32_16x16x32_bf16(af[m], bfr[n], acc[m][n], 0, 0, 0);
  }

  // epilogue: C/D layout col=lane&15, row=(lane>>4)*4+j  [m89/m91]
#pragma unroll
  for (int m = 0; m < 4; ++m) {
    const int row = brow + wr * 64 + m * 16 + g * 4;
#pragma unroll
    for (int n = 0; n < 4; ++n) {
      const int col = bcol + wc * 64 + n * 16 + fr;
      const float bv = (col < biasN) ? bias[col] : 0.f;
#pragma unroll
      for (int j = 0; j < 4; ++j) {
        float v = acc[m][n][j] + bv;
        if (relu) v = fmaxf(v, 0.f);
        C[(size_t)(row + j) * ldc + col] = f2bf(v);
      }
    }
  }
}

// ---------------------------------------------------------------- conversions
__global__ __launch_bounds__(256)
void cvt_pad(const float* __restrict__ in, uint16_t* __restrict__ out, int cols, int colsPad)
{
  const int r = blockIdx.y;
  const int c = (blockIdx.x * 256 + threadIdx.x) * 2;
  if (c >= colsPad) return;
  const float* ip = in + (size_t)r * cols;
  const float v0 = (c < cols)     ? ip[c]     : 0.f;
  const float v1 = (c + 1 < cols) ? ip[c + 1] : 0.f;
  const uint32_t pk = (uint32_t)f2bf(v0) | ((uint32_t)f2bf(v1) << 16);
  *(uint32_t*)(out + (size_t)r * colsPad + c) = pk;
}

// W[K][N] f32 -> Wt[Np][Kp] bf16 (transpose + pad). grid (Kp/32, Np/32), block (32,8)
__global__ __launch_bounds__(256)
void transpose_w(const float* __restrict__ W, uint16_t* __restrict__ Wt,
                 int K, int N, int Kp, int Np)
{
  __shared__ float t[32][33];
  const int tx = threadIdx.x, ty = threadIdx.y;
  const int k0 = blockIdx.x * 32, n0 = blockIdx.y * 32;
#pragma unroll
  for (int j = 0; j < 4; ++j) {
    const int k = k0 + ty + j * 8, n = n0 + tx;
    t[ty + j * 8][tx] = (k < K && n < N) ? W[(size_t)k * N + n] : 0.f;
  }
  __syncthreads();
#pragma unroll
  for (int j = 0; j < 4; ++j) {
    const int n = n0 + ty + j * 8, k = k0 + tx;
    Wt[(size_t)n * Kp + k] = f2bf(t[tx][ty + j * 8]);
  }
}

// ---------------------------------------------------------------- CSR build
__global__ void count_deg(const int* __restrict__ ei, int* __restrict__ counts)
{
  const int e = blockIdx.x * 256 + threadIdx.x;
  if (e >= ET) return;
  const int d = (e < NE) ? ei[NE + e] : (e - NE);
  atomicAdd(&counts[d], 1);
}

__global__ __launch_bounds__(1024)
void scan_deg(const int* __restrict__ counts, int* __restrict__ row_start, int* __restrict__ cursor)
{
  __shared__ int part[1024];
  const int tid = threadIdx.x;
  int loc[8], pre[8], s = 0;
#pragma unroll
  for (int j = 0; j < 8; ++j) { loc[j] = counts[tid * 8 + j]; pre[j] = s; s += loc[j]; }
  part[tid] = s;
  __syncthreads();
  for (int o = 1; o < 1024; o <<= 1) {
    const int v = part[tid];
    const int a = (tid >= o) ? part[tid - o] : 0;
    __syncthreads();
    part[tid] = v + a;
    __syncthreads();
  }
  const int excl = part[tid] - s;
#pragma unroll
  for (int j = 0; j < 8; ++j) {
    const int v = excl + pre[j];
    row_start[tid * 8 + j] = v;
    cursor[tid * 8 + j]    = v;
  }
  if (tid == 1023) row_start[8192] = excl + s;
}

__global__ void scatter_e(const int* __restrict__ ei, int* __restrict__ cursor,
                          int* __restrict__ csr_src, int* __restrict__ csr_dst)
{
  const int e = blockIdx.x * 256 + threadIdx.x;
  if (e >= ET) return;
  const int sx = (e < NE) ? ei[e]      : (e - NE);
  const int d  = (e < NE) ? ei[NE + e] : (e - NE);
  const int pos = atomicAdd(&cursor[d], 1);
  csr_src[pos] = sx;
  csr_dst[pos] = d;
}

// ---------------------------------------------------------------- GATv2 attention
// logit[slot][h] = sum_c att[h][c] * leaky_relu(xl[src][h,c] + xr[dst][h,c])
__global__ __launch_bounds__(256)
void gat_logits(const uint16_t* __restrict__ xl, const uint16_t* __restrict__ xr,
                const int* __restrict__ csr_src, const int* __restrict__ csr_dst,
                const float* __restrict__ att, float* __restrict__ logit)
{
  const int slot = (blockIdx.x << 2) + (threadIdx.x >> 6);
  if (slot >= ET) return;
  const int lane = threadIdx.x & 63;
  const uint32_t* pl = (const uint32_t*)(xl + (size_t)csr_src[slot] * 1536);
  const uint32_t* pr = (const uint32_t*)(xr + (size_t)csr_dst[slot] * 1536);
  const float2* a2 = (const float2*)att;
  float acc0 = 0.f, acc1 = 0.f, acc2 = 0.f;
#pragma unroll
  for (int it = 0; it < 12; ++it) {
    const int idx = lane + it * 64;          // pair index; head = it>>2
    const uint32_t ul = pl[idx], ur = pr[idx];
    const float2 av = a2[idx];
    float v0 = bf2f((uint16_t)ul)         + bf2f((uint16_t)ur);
    float v1 = bf2f((uint16_t)(ul >> 16)) + bf2f((uint16_t)(ur >> 16));
    v0 = v0 > 0.f ? v0 : 0.2f * v0;
    v1 = v1 > 0.f ? v1 : 0.2f * v1;
    const float p = v0 * av.x + v1 * av.y;
    if (it < 4) acc0 += p; else if (it < 8) acc1 += p; else acc2 += p;
  }
#pragma unroll
  for (int o = 32; o; o >>= 1) {
    acc0 += __shfl_xor(acc0, o);
    acc1 += __shfl_xor(acc1, o);
    acc2 += __shfl_xor(acc2, o);
  }
  if (lane == 0) {
    float* op = logit + (size_t)slot * 3;
    op[0] = acc0; op[1] = acc1; op[2] = acc2;
  }
}

// out[i][c] = relu( sum_slots softmax(logit)[slot][h(c)] * xl[src][c] + ob[c] )
__global__ __launch_bounds__(256)
void gat_aggregate(const float* __restrict__ logit, const int* __restrict__ csr_src,
                   const int* __restrict__ row_start, const uint16_t* __restrict__ xl,
                   const float* __restrict__ ob, uint16_t* __restrict__ out, int ldc)
{
  const int i = blockIdx.x;
  const int tid = threadIdx.x;
  const int s0 = row_start[i], s1 = row_start[i + 1];

  // online softmax stats per head, computed redundantly by every thread (broadcast loads)
  float m0 = -1e30f, m1 = -1e30f, m2 = -1e30f, z0 = 0.f, z1 = 0.f, z2 = 0.f;
  for (int s = s0; s < s1; ++s) {
    const float* lp = logit + (size_t)s * 3;
    float l0 = lp[0], l1 = lp[1], l2 = lp[2];
    float n0 = fmaxf(m0, l0); z0 = z0 * __expf(m0 - n0) + __expf(l0 - n0); m0 = n0;
    float n1 = fmaxf(m1, l1); z1 = z1 * __expf(m1 - n1) + __expf(l1 - n1); m1 = n1;
    float n2 = fmaxf(m2, l2); z2 = z2 * __expf(m2 - n2) + __expf(l2 - n2); m2 = n2;
  }
  const float r0 = 1.f / z0, r1 = 1.f / z1, r2 = 1.f / z2;

  float acc[6] = {0.f, 0.f, 0.f, 0.f, 0.f, 0.f};
  for (int s = s0; s < s1; ++s) {
    const float* lp = logit + (size_t)s * 3;
    const float w0 = __expf(lp[0] - m0) * r0;
    const float w1 = __expf(lp[1] - m1) * r1;
    const float w2 = __expf(lp[2] - m2) * r2;
    const uint16_t* px = xl + (size_t)csr_src[s] * 1536;
    acc[0] += w0 * bf2f(px[tid]);        acc[1] += w0 * bf2f(px[tid + 256]);
    acc[2] += w1 * bf2f(px[tid + 512]);  acc[3] += w1 * bf2f(px[tid + 768]);
    acc[4] += w2 * bf2f(px[tid + 1024]); acc[5] += w2 * bf2f(px[tid + 1280]);
  }
#pragma unroll
  for (int j = 0; j < 6; ++j) {
    const int c = tid + j * 256;
    float v = acc[j] + ob[c];
    v = fmaxf(v, 0.f);
    out[(size_t)i * ldc + c] = f2bf(v);
  }
}

// ---------------------------------------------------------------- final dot (K=512 -> 1)
__global__ __launch_bounds__(256)
void final_dot(const uint16_t* __restrict__ z2, const float* __restrict__ w,
               const float* __restrict__ b, float* __restrict__ out)
{
  const int row  = blockIdx.x * 4 + (threadIdx.x >> 6);
  const int lane = threadIdx.x & 63;
  const uint16_t* p = z2 + (size_t)row * 512;
  float s = 0.f;
#pragma unroll
  for (int j = 0; j < 8; ++j) { const int c = lane + j * 64; s += bf2f(p[c]) * w[c]; }
#pragma unroll
  for (int o = 32; o; o >>= 1) s += __shfl_xor(s, o);
  if (lane == 0) out[row] = s + b[0];
}

// ---------------------------------------------------------------- orchestration
extern "C" void kernel_launch(void* const* d_in, const int* in_sizes, int n_in,
                              void* d_out, int out_size, void* d_ws, size_t ws_size,
                              hipStream_t stream)
{
  (void)in_sizes; (void)n_in; (void)out_size; (void)ws_size;

  const float* x    = (const float*)d_in[0];
  const int*   ei   = (const int*)  d_in[1];
  const float* expm = (const float*)d_in[2];
  const float* w1l = (const float*)d_in[3];  const float* b1l = (const float*)d_in[4];
  const float* w1r = (const float*)d_in[5];  const float* b1r = (const float*)d_in[6];
  const float* a1  = (const float*)d_in[7];  const float* o1  = (const float*)d_in[8];
  const float* w2l = (const float*)d_in[9];  const float* b2l = (const float*)d_in[10];
  const float* w2r = (const float*)d_in[11]; const float* b2r = (const float*)d_in[12];
  const float* a2  = (const float*)d_in[13]; const float* o2  = (const float*)d_in[14];
  const float* w3l = (const float*)d_in[15]; const float* b3l = (const float*)d_in[16];
  const float* w3r = (const float*)d_in[17]; const float* b3r = (const float*)d_in[18];
  const float* a3  = (const float*)d_in[19]; const float* o3  = (const float*)d_in[20];
  const float* e1w = (const float*)d_in[21]; const float* e1b = (const float*)d_in[22];
  const float* e2w = (const float*)d_in[23]; const float* e2b = (const float*)d_in[24];
  const float* e3w = (const float*)d_in[25]; const float* e3b = (const float*)d_in[26];
  const float* l1w = (const float*)d_in[27]; const float* l1b = (const float*)d_in[28];
  const float* l2w = (const float*)d_in[29]; const float* l2b = (const float*)d_in[30];
  const float* l3w = (const float*)d_in[31]; const float* l3b = (const float*)d_in[32];
  float* out = (float*)d_out;

  // ---- workspace layout (~325 MB, phase-reused regions)
  char* ws = (char*)d_ws;
  size_t off = 0;
  auto take = [&](size_t b) { char* p = ws + off; off += (b + 255) & ~(size_t)255; return p; };

  int*      counts    = (int*)take((size_t)NN * 4);
  int*      row_start = (int*)take((size_t)(NN + 1) * 4);
  int*      cursor    = (int*)take((size_t)NN * 4);
  int*      csr_src   = (int*)take((size_t)ET * 4);
  int*      csr_dst   = (int*)take((size_t)ET * 4);
  float*    logits    = (float*)take((size_t)ET * 3 * 4);
  uint16_t* zbuf      = (uint16_t*)take((size_t)NN * 2048 * 2);
  char*     regA      = take((size_t)NN * F_EXP_P * 2);                       // x_bf16 / exp_bf16
  char*     regW      = take((size_t)4096 * F_EXP_P * 2);                     // one transposed weight
  char*     regC      = take((size_t)NN * 4096 * 2 + (size_t)NN * 1536 * 2);  // xl/xr/h | cell1/cell2 | z1/z2

  const size_t HCB = (size_t)NN * 1536 * 2;
  uint16_t* xbf   = (uint16_t*)regA;
  uint16_t* expbf = (uint16_t*)regA;
  uint16_t* wT    = (uint16_t*)regW;
  uint16_t* xlb   = (uint16_t*)regC;
  uint16_t* xrb   = (uint16_t*)(regC + HCB);
  uint16_t* hbuf  = (uint16_t*)(regC + 2 * HCB);
  uint16_t* cell1 = (uint16_t*)regC;
  uint16_t* cell2 = (uint16_t*)(regC + (size_t)NN * 4096 * 2);
  uint16_t* zz1   = (uint16_t*)regC;
  uint16_t* zz2   = (uint16_t*)(regC + (size_t)NN * 1024 * 2);

  // ---- CSR (shared by all 3 GAT layers)
  hipMemsetAsync(counts, 0, (size_t)NN * 4, stream);
  count_deg<<<(ET + 255) / 256, 256, 0, stream>>>(ei, counts);
  scan_deg<<<1, 1024, 0, stream>>>(counts, row_start, cursor);
  scatter_e<<<(ET + 255) / 256, 256, 0, stream>>>(ei, cursor, csr_src, csr_dst);

  // ---- GAT layer 1 (K = 3264 padded)
  cvt_pad<<<dim3((F_IN_P / 2 + 255) / 256, NN), 256, 0, stream>>>(x, xbf, F_IN, F_IN_P);
  transpose_w<<<dim3(F_IN_P / 32, 1536 / 32), dim3(32, 8), 0, stream>>>(w1l, wT, F_IN, 1536, F_IN_P, 1536);
  gemm_bt<<<dim3(64, 12), 256, 0, stream>>>(xbf, wT, b1l, 1536, 0, xlb, F_IN_P, 1536);
  transpose_w<<<dim3(F_IN_P / 32, 1536 / 32), dim3(32, 8), 0, stream>>>(w1r, wT, F_IN, 1536, F_IN_P, 1536);
  gemm_bt<<<dim3(64, 12), 256, 0, stream>>>(xbf, wT, b1r, 1536, 0, xrb, F_IN_P, 1536);
  gat_logits<<<ET / 4, 256, 0, stream>>>(xlb, xrb, csr_src, csr_dst, a1, logits);
  gat_aggregate<<<NN, 256, 0, stream>>>(logits, csr_src, row_start, xlb, o1, hbuf, 1536);

  // ---- GAT layer 2 (K = 1536)
  transpose_w<<<dim3(48, 48), dim3(32, 8), 0, stream>>>(w2l, wT, 1536, 1536, 1536, 1536);
  gemm_bt<<<dim3(64, 12), 256, 0, stream>>>(hbuf, wT, b2l, 1536, 0, xlb, 1536, 1536);
  transpose_w<<<dim3(48, 48), dim3(32, 8), 0, stream>>>(w2r, wT, 1536, 1536, 1536, 1536);
  gemm_bt<<<dim3(64, 12), 256, 0, stream>>>(hbuf, wT, b2r, 1536, 0, xrb, 1536, 1536);
  gat_logits<<<ET / 4, 256, 0, stream>>>(xlb, xrb, csr_src, csr_dst, a2, logits);
  gat_aggregate<<<NN, 256, 0, stream>>>(logits, csr_src, row_start, xlb, o2, hbuf, 1536);

  // ---- GAT layer 3 -> zbuf cols [0,1536)
  transpose_w<<<dim3(48, 48), dim3(32, 8), 0, stream>>>(w3l, wT, 1536, 1536, 1536, 1536);
  gemm_bt<<<dim3(64, 12), 256, 0, stream>>>(hbuf, wT, b3l, 1536, 0, xlb, 1536, 1536);
  transpose_w<<<dim3(48, 48), dim3(32, 8), 0, stream>>>(w3r, wT, 1536, 1536, 1536, 1536);
  gemm_bt<<<dim3(64, 12), 256, 0, stream>>>(hbuf, wT, b3r, 1536, 0, xrb, 1536, 1536);
  gat_logits<<<ET / 4, 256, 0, stream>>>(xlb, xrb, csr_src, csr_dst, a3, logits);
  gat_aggregate<<<NN, 256, 0, stream>>>(logits, csr_src, row_start, xlb, o3, zbuf, 2048);

  // ---- expression encoder: 7993 -> 4000 -> 1500 -> 512, last into zbuf cols [1536,2048)
  cvt_pad<<<dim3((F_EXP_P / 2 + 255) / 256, NN), 256, 0, stream>>>(expm, expbf, F_EXP, F_EXP_P);
  transpose_w<<<dim3(F_EXP_P / 32, 4096 / 32), dim3(32, 8), 0, stream>>>(e1w, wT, F_EXP, 4000, F_EXP_P, 4096);
  gemm_bt<<<dim3(64, 32), 256, 0, stream>>>(expbf, wT, e1b, 4000, 1, cell1, F_EXP_P, 4096);
  transpose_w<<<dim3(4096 / 32, 1536 / 32), dim3(32, 8), 0, stream>>>(e2w, wT, 4000, 1500, 4096, 1536);
  gemm_bt<<<dim3(64, 12), 256, 0, stream>>>(cell1, wT, e2b, 1500, 1, cell2, 4096, 1536);
  transpose_w<<<dim3(1536 / 32, 512 / 32), dim3(32, 8), 0, stream>>>(e3w, wT, 1500, 512, 1536, 512);
  gemm_bt<<<dim3(64, 4), 256, 0, stream>>>(cell2, wT, e3b, 512, 0, zbuf + 1536, 1536, 2048);

  // ---- head: 2048 -> 1024 -> 512 -> 1
  transpose_w<<<dim3(2048 / 32, 1024 / 32), dim3(32, 8), 0, stream>>>(l1w, wT, 2048, 1024, 2048, 1024);
  gemm_bt<<<dim3(64, 8), 256, 0, stream>>>(zbuf, wT, l1b, 1024, 1, zz1, 2048, 1024);
  transpose_w<<<dim3(1024 / 32, 512 / 32), dim3(32, 8), 0, stream>>>(l2w, wT, 1024, 512, 1024, 512);
  gemm_bt<<<dim3(64, 4), 256, 0, stream>>>(zz1, wT, l2b, 512, 1, zz2, 1024, 512);
  final_dot<<<NN / 4, 256, 0, stream>>>(zz2, l3w, l3b, out);
}

// Round 2
// 1698.869 us; speedup vs baseline: 1.1374x; 1.1374x over previous
//
#include <hip/hip_runtime.h>
#include <stdint.h>

#define NN 8192
#define NE 65536
#define ET (NE + NN)
#define F_IN   3247
#define F_IN_P 3264
#define F_EXP   7993
#define F_EXP_P 8000

typedef __attribute__((ext_vector_type(8))) short bf16x8;
typedef __attribute__((ext_vector_type(4))) float f32x4;

typedef const __attribute__((address_space(1))) void gvoid_t;
typedef __attribute__((address_space(3))) void lvoid_t;

__device__ __forceinline__ float bf2f(uint16_t u) {
  union { uint32_t i; float f; } v; v.i = ((uint32_t)u) << 16; return v.f;
}
__device__ __forceinline__ uint16_t f2bf(float f) {
  union { float f; uint32_t i; } v; v.f = f;
  uint32_t r = v.i + 0x7fffu + ((v.i >> 16) & 1u);  // RNE
  return (uint16_t)(r >> 16);
}

__device__ __forceinline__ void gld_lds16(const void* g, void* l) {
  __builtin_amdgcn_global_load_lds((gvoid_t*)g, (lvoid_t*)l, 16, 0, 0);
}

#define BARRIER() do { __builtin_amdgcn_sched_barrier(0); \
                       __builtin_amdgcn_s_barrier(); \
                       __builtin_amdgcn_sched_barrier(0); } while (0)
#define LGKM0()   do { asm volatile("s_waitcnt lgkmcnt(0)" ::: "memory"); \
                       __builtin_amdgcn_sched_barrier(0); } while (0)

// =================================================================== gemm256
// 256x256 tile, BK=64, 8 waves (2M x 4N), 4-phase K-loop, T2 swizzle,
// counted vmcnt(8), setprio around MFMA clusters. Dynamic LDS = 128 KiB.
// C[M][ldc] = A[M][Kp] * Bt[Np][Kp]^T + bias (+relu).  M%256==0, N%256==0, Kp%64==0.
__device__ __forceinline__ void stage4(const char* src, char* dst, size_t Kb) {
#pragma unroll
  for (int j = 0; j < 4; ++j)
    gld_lds16(src + (size_t)(j * 64) * Kb, dst + j * 8192);
}

__global__ __launch_bounds__(512, 2)
void gemm256(const uint16_t* __restrict__ A, const uint16_t* __restrict__ Bt,
             const float* __restrict__ bias, int biasN, int relu,
             uint16_t* __restrict__ C, int Kp, int ldc, int nbn)
{
  extern __shared__ char smem[];   // [A: 2buf x 256 x 128B = 64K][B: same = 64K]
  const int tid = threadIdx.x;
  const int w = tid >> 6, lane = tid & 63;
  const int wr = w >> 2, wc = w & 3;
  const int fr = lane & 15, g = lane >> 4;

  // T1: bijective XCD swizzle of linear block id
  const int nwg = (int)gridDim.x;
  const int id = (int)blockIdx.x;
  const int q = nwg >> 3, r = nwg & 7;
  const int xcd = id & 7, idx = id >> 3;
  const int wg = (xcd < r ? xcd * (q + 1) : r * (q + 1) + (xcd - r) * q) + idx;
  const int brow = (wg / nbn) * 256, bcol = (wg % nbn) * 256;

  const size_t Kb = (size_t)Kp * 2;  // row bytes

  // staging: thread tid -> LDS linear offset j*8192 + tid*16
  //   row = j*64 + (tid>>3), linear slot = tid&7; source slot = slot ^ (row&7)
  const int srow = tid >> 3;
  const int sswz = ((tid & 7) ^ (srow & 7)) * 16;
  const char* pA = (const char*)A + (size_t)(brow + srow) * Kb + sswz;
  const char* pB = (const char*)Bt + (size_t)(bcol + srow) * Kb + sswz;
  char* sA = smem + w * 1024;            // + buf*32768 + j*8192 (lane*16 by HW)
  char* sB = smem + 65536 + w * 1024;

  // frag-read swizzled slot offsets: slot = (kk*4+g) ^ (row&7), row&7 == fr&7
  const int sw0 = ((g) ^ (fr & 7)) * 16;
  const int sw1 = ((g + 4) ^ (fr & 7)) * 16;
  const int arow = (wr * 128 + fr) * 128;   // + m*2048
  const int brow_o = (wc * 64 + fr) * 128;  // + n*2048

  f32x4 acc[8][4];
#pragma unroll
  for (int m = 0; m < 8; ++m)
#pragma unroll
    for (int n = 0; n < 4; ++n) acc[m][n] = (f32x4){0.f, 0.f, 0.f, 0.f};
  bf16x8 af[8][2], bg[4][2];

  // prologue: stage tiles 0 and 1 (16 issues/wave), wait oldest 8 (tile 0)
  stage4(pA, sA, Kb);
  stage4(pB, sB, Kb);
  stage4(pA + 128, sA + 32768, Kb);
  stage4(pB + 128, sB + 32768, Kb);
  asm volatile("s_waitcnt vmcnt(8)" ::: "memory");
  BARRIER();

  const int nk = Kp >> 6;
  for (int t = 0; t < nk; ++t) {
    const int buf = (t & 1) << 15;
    const char* aB = smem + buf + arow;
    const char* bB = smem + 65536 + buf + brow_o;

    // ---- ph0: read a[0..3], b[0..1]; MFMA m0-3 x n0-1
#pragma unroll
    for (int m = 0; m < 4; ++m) {
      af[m][0] = *(const bf16x8*)(aB + m * 2048 + sw0);
      af[m][1] = *(const bf16x8*)(aB + m * 2048 + sw1);
    }
#pragma unroll
    for (int n = 0; n < 2; ++n) {
      bg[n][0] = *(const bf16x8*)(bB + n * 2048 + sw0);
      bg[n][1] = *(const bf16x8*)(bB + n * 2048 + sw1);
    }
    BARRIER(); LGKM0();
    __builtin_amdgcn_s_setprio(1);
#pragma unroll
    for (int m = 0; m < 4; ++m)
#pragma unroll
      for (int n = 0; n < 2; ++n) {
        acc[m][n] = __builtin_amdgcn_mfma_f32_16x16x32_bf16(af[m][0], bg[n][0], acc[m][n], 0, 0, 0);
        acc[m][n] = __builtin_amdgcn_mfma_f32_16x16x32_bf16(af[m][1], bg[n][1], acc[m][n], 0, 0, 0);
      }
    __builtin_amdgcn_s_setprio(0);
    BARRIER();

    // ---- ph1: read a[4..7], b[2..3]; MFMA m4-7 x n0-1
#pragma unroll
    for (int m = 4; m < 8; ++m) {
      af[m][0] = *(const bf16x8*)(aB + m * 2048 + sw0);
      af[m][1] = *(const bf16x8*)(aB + m * 2048 + sw1);
    }
#pragma unroll
    for (int n = 2; n < 4; ++n) {
      bg[n][0] = *(const bf16x8*)(bB + n * 2048 + sw0);
      bg[n][1] = *(const bf16x8*)(bB + n * 2048 + sw1);
    }
    BARRIER(); LGKM0();
    __builtin_amdgcn_s_setprio(1);
#pragma unroll
    for (int m = 4; m < 8; ++m)
#pragma unroll
      for (int n = 0; n < 2; ++n) {
        acc[m][n] = __builtin_amdgcn_mfma_f32_16x16x32_bf16(af[m][0], bg[n][0], acc[m][n], 0, 0, 0);
        acc[m][n] = __builtin_amdgcn_mfma_f32_16x16x32_bf16(af[m][1], bg[n][1], acc[m][n], 0, 0, 0);
      }
    __builtin_amdgcn_s_setprio(0);
    BARRIER();

    // ---- ph2: stage A(t+2); MFMA m0-3 x n2-3
    if (t + 2 < nk) stage4(pA + (size_t)(t + 2) * 128, sA + (((t + 2) & 1) << 15), Kb);
    BARRIER();
    __builtin_amdgcn_s_setprio(1);
#pragma unroll
    for (int m = 0; m < 4; ++m)
#pragma unroll
      for (int n = 2; n < 4; ++n) {
        acc[m][n] = __builtin_amdgcn_mfma_f32_16x16x32_bf16(af[m][0], bg[n][0], acc[m][n], 0, 0, 0);
        acc[m][n] = __builtin_amdgcn_mfma_f32_16x16x32_bf16(af[m][1], bg[n][1], acc[m][n], 0, 0, 0);
      }
    __builtin_amdgcn_s_setprio(0);
    BARRIER();

    // ---- ph3: stage B(t+2); MFMA m4-7 x n2-3; counted vmcnt
    if (t + 2 < nk) stage4(pB + (size_t)(t + 2) * 128, sB + (((t + 2) & 1) << 15), Kb);
    BARRIER();
    __builtin_amdgcn_s_setprio(1);
#pragma unroll
    for (int m = 4; m < 8; ++m)
#pragma unroll
      for (int n = 2; n < 4; ++n) {
        acc[m][n] = __builtin_amdgcn_mfma_f32_16x16x32_bf16(af[m][0], bg[n][0], acc[m][n], 0, 0, 0);
        acc[m][n] = __builtin_amdgcn_mfma_f32_16x16x32_bf16(af[m][1], bg[n][1], acc[m][n], 0, 0, 0);
      }
    __builtin_amdgcn_s_setprio(0);
    if (t + 2 < nk) { asm volatile("s_waitcnt vmcnt(8)" ::: "memory"); }
    else            { asm volatile("s_waitcnt vmcnt(0)" ::: "memory"); }
    BARRIER();
  }

  // epilogue: C/D layout col=lane&15, row=(lane>>4)*4+j
#pragma unroll
  for (int m = 0; m < 8; ++m) {
    const int row = brow + wr * 128 + m * 16 + g * 4;
#pragma unroll
    for (int n = 0; n < 4; ++n) {
      const int col = bcol + wc * 64 + n * 16 + fr;
      const float bv = (col < biasN) ? bias[col] : 0.f;
#pragma unroll
      for (int j = 0; j < 4; ++j) {
        float v = acc[m][n][j] + bv;
        if (relu) v = fmaxf(v, 0.f);
        C[(size_t)(row + j) * ldc + col] = f2bf(v);
      }
    }
  }
}

// ---------------------------------------------------------------- GEMM (m97 structure, small N)
__global__ __launch_bounds__(256)
void gemm_bt(const uint16_t* __restrict__ A, const uint16_t* __restrict__ Bt,
             const float* __restrict__ bias, int biasN, int relu,
             uint16_t* __restrict__ C, int Kp, int ldc)
{
  __shared__ uint16_t As[128 * 32];
  __shared__ uint16_t Bs[128 * 32];
  const int tid  = threadIdx.x;
  const int wave = tid >> 6, lane = tid & 63;
  const int brow = blockIdx.x * 128, bcol = blockIdx.y * 128;
  const int wr = wave >> 1, wc = wave & 1;
  const int fr = lane & 15, g = lane >> 4;

  f32x4 acc[4][4];
#pragma unroll
  for (int m = 0; m < 4; ++m)
#pragma unroll
    for (int n = 0; n < 4; ++n) acc[m][n] = (f32x4){0.f, 0.f, 0.f, 0.f};

  const int rA = tid >> 2;
  const int kc = (tid & 3) * 8;
  const uint16_t* aptr = A  + (size_t)(brow + rA) * Kp + kc;
  const uint16_t* bptr = Bt + (size_t)(bcol + rA) * Kp + kc;
  char* ldsA = (char*)As + wave * 1024;
  char* ldsB = (char*)Bs + wave * 1024;
  const size_t rowskip = (size_t)64 * Kp;

  const int nk = Kp >> 5;
  for (int kt = 0; kt < nk; ++kt) {
    __syncthreads();
    gld_lds16(aptr,           ldsA);
    gld_lds16(aptr + rowskip, ldsA + 4096);
    gld_lds16(bptr,           ldsB);
    gld_lds16(bptr + rowskip, ldsB + 4096);
    aptr += 32; bptr += 32;
    __syncthreads();

    bf16x8 af[4], bfr[4];
#pragma unroll
    for (int m = 0; m < 4; ++m)
      af[m] = *(const bf16x8*)&As[(wr * 64 + m * 16 + fr) * 32 + g * 8];
#pragma unroll
    for (int n = 0; n < 4; ++n)
      bfr[n] = *(const bf16x8*)&Bs[(wc * 64 + n * 16 + fr) * 32 + g * 8];
#pragma unroll
    for (int m = 0; m < 4; ++m)
#pragma unroll
      for (int n = 0; n < 4; ++n)
        acc[m][n] = __builtin_amdgcn_mfma_f32_16x16x32_bf16(af[m], bfr[n], acc[m][n], 0, 0, 0);
  }

#pragma unroll
  for (int m = 0; m < 4; ++m) {
    const int row = brow + wr * 64 + m * 16 + g * 4;
#pragma unroll
    for (int n = 0; n < 4; ++n) {
      const int col = bcol + wc * 64 + n * 16 + fr;
      const float bv = (col < biasN) ? bias[col] : 0.f;
#pragma unroll
      for (int j = 0; j < 4; ++j) {
        float v = acc[m][n][j] + bv;
        if (relu) v = fmaxf(v, 0.f);
        C[(size_t)(row + j) * ldc + col] = f2bf(v);
      }
    }
  }
}

// ---------------------------------------------------------------- conversions
__global__ __launch_bounds__(256)
void cvt_pad(const float* __restrict__ in, uint16_t* __restrict__ out, int cols, int colsPad)
{
  const int r = blockIdx.y;
  const int c = (blockIdx.x * 256 + threadIdx.x) * 2;
  if (c >= colsPad) return;
  const float* ip = in + (size_t)r * cols;
  const float v0 = (c < cols)     ? ip[c]     : 0.f;
  const float v1 = (c + 1 < cols) ? ip[c + 1] : 0.f;
  const uint32_t pk = (uint32_t)f2bf(v0) | ((uint32_t)f2bf(v1) << 16);
  *(uint32_t*)(out + (size_t)r * colsPad + c) = pk;
}

__global__ __launch_bounds__(256)
void transpose_w(const float* __restrict__ W, uint16_t* __restrict__ Wt,
                 int K, int N, int Kp, int Np)
{
  __shared__ float t[32][33];
  const int tx = threadIdx.x, ty = threadIdx.y;
  const int k0 = blockIdx.x * 32, n0 = blockIdx.y * 32;
#pragma unroll
  for (int j = 0; j < 4; ++j) {
    const int k = k0 + ty + j * 8, n = n0 + tx;
    t[ty + j * 8][tx] = (k < K && n < N) ? W[(size_t)k * N + n] : 0.f;
  }
  __syncthreads();
#pragma unroll
  for (int j = 0; j < 4; ++j) {
    const int n = n0 + ty + j * 8, k = k0 + tx;
    Wt[(size_t)n * Kp + k] = f2bf(t[tx][ty + j * 8]);
  }
}

// ---------------------------------------------------------------- CSR build
__global__ void count_deg(const int* __restrict__ ei, int* __restrict__ counts)
{
  const int e = blockIdx.x * 256 + threadIdx.x;
  if (e >= ET) return;
  const int d = (e < NE) ? ei[NE + e] : (e - NE);
  atomicAdd(&counts[d], 1);
}

__global__ __launch_bounds__(1024)
void scan_deg(const int* __restrict__ counts, int* __restrict__ row_start, int* __restrict__ cursor)
{
  __shared__ int part[1024];
  const int tid = threadIdx.x;
  int loc[8], pre[8], s = 0;
#pragma unroll
  for (int j = 0; j < 8; ++j) { loc[j] = counts[tid * 8 + j]; pre[j] = s; s += loc[j]; }
  part[tid] = s;
  __syncthreads();
  for (int o = 1; o < 1024; o <<= 1) {
    const int v = part[tid];
    const int a = (tid >= o) ? part[tid - o] : 0;
    __syncthreads();
    part[tid] = v + a;
    __syncthreads();
  }
  const int excl = part[tid] - s;
#pragma unroll
  for (int j = 0; j < 8; ++j) {
    const int v = excl + pre[j];
    row_start[tid * 8 + j] = v;
    cursor[tid * 8 + j]    = v;
  }
  if (tid == 1023) row_start[8192] = excl + s;
}

__global__ void scatter_e(const int* __restrict__ ei, int* __restrict__ cursor,
                          int* __restrict__ csr_src, int* __restrict__ csr_dst)
{
  const int e = blockIdx.x * 256 + threadIdx.x;
  if (e >= ET) return;
  const int sx = (e < NE) ? ei[e]      : (e - NE);
  const int d  = (e < NE) ? ei[NE + e] : (e - NE);
  const int pos = atomicAdd(&cursor[d], 1);
  csr_src[pos] = sx;
  csr_dst[pos] = d;
}

// ---------------------------------------------------------------- GATv2 attention
__global__ __launch_bounds__(256)
void gat_logits(const uint16_t* __restrict__ xl, const uint16_t* __restrict__ xr,
                const int* __restrict__ csr_src, const int* __restrict__ csr_dst,
                const float* __restrict__ att, float* __restrict__ logit)
{
  const int slot = (blockIdx.x << 2) + (threadIdx.x >> 6);
  if (slot >= ET) return;
  const int lane = threadIdx.x & 63;
  const uint32_t* pl = (const uint32_t*)(xl + (size_t)csr_src[slot] * 1536);
  const uint32_t* pr = (const uint32_t*)(xr + (size_t)csr_dst[slot] * 1536);
  const float2* a2 = (const float2*)att;
  float acc0 = 0.f, acc1 = 0.f, acc2 = 0.f;
#pragma unroll
  for (int it = 0; it < 12; ++it) {
    const int idx = lane + it * 64;
    const uint32_t ul = pl[idx], ur = pr[idx];
    const float2 av = a2[idx];
    float v0 = bf2f((uint16_t)ul)         + bf2f((uint16_t)ur);
    float v1 = bf2f((uint16_t)(ul >> 16)) + bf2f((uint16_t)(ur >> 16));
    v0 = v0 > 0.f ? v0 : 0.2f * v0;
    v1 = v1 > 0.f ? v1 : 0.2f * v1;
    const float p = v0 * av.x + v1 * av.y;
    if (it < 4) acc0 += p; else if (it < 8) acc1 += p; else acc2 += p;
  }
#pragma unroll
  for (int o = 32; o; o >>= 1) {
    acc0 += __shfl_xor(acc0, o);
    acc1 += __shfl_xor(acc1, o);
    acc2 += __shfl_xor(acc2, o);
  }
  if (lane == 0) {
    float* op = logit + (size_t)slot * 3;
    op[0] = acc0; op[1] = acc1; op[2] = acc2;
  }
}

__global__ __launch_bounds__(256)
void gat_aggregate(const float* __restrict__ logit, const int* __restrict__ csr_src,
                   const int* __restrict__ row_start, const uint16_t* __restrict__ xl,
                   const float* __restrict__ ob, uint16_t* __restrict__ out, int ldc)
{
  const int i = blockIdx.x;
  const int tid = threadIdx.x;
  const int s0 = row_start[i], s1 = row_start[i + 1];

  float m0 = -1e30f, m1 = -1e30f, m2 = -1e30f, z0 = 0.f, z1 = 0.f, z2 = 0.f;
  for (int s = s0; s < s1; ++s) {
    const float* lp = logit + (size_t)s * 3;
    float l0 = lp[0], l1 = lp[1], l2 = lp[2];
    float n0 = fmaxf(m0, l0); z0 = z0 * __expf(m0 - n0) + __expf(l0 - n0); m0 = n0;
    float n1 = fmaxf(m1, l1); z1 = z1 * __expf(m1 - n1) + __expf(l1 - n1); m1 = n1;
    float n2 = fmaxf(m2, l2); z2 = z2 * __expf(m2 - n2) + __expf(l2 - n2); m2 = n2;
  }
  const float r0 = 1.f / z0, r1 = 1.f / z1, r2 = 1.f / z2;

  float acc[6] = {0.f, 0.f, 0.f, 0.f, 0.f, 0.f};
  for (int s = s0; s < s1; ++s) {
    const float* lp = logit + (size_t)s * 3;
    const float w0 = __expf(lp[0] - m0) * r0;
    const float w1 = __expf(lp[1] - m1) * r1;
    const float w2 = __expf(lp[2] - m2) * r2;
    const uint16_t* px = xl + (size_t)csr_src[s] * 1536;
    acc[0] += w0 * bf2f(px[tid]);        acc[1] += w0 * bf2f(px[tid + 256]);
    acc[2] += w1 * bf2f(px[tid + 512]);  acc[3] += w1 * bf2f(px[tid + 768]);
    acc[4] += w2 * bf2f(px[tid + 1024]); acc[5] += w2 * bf2f(px[tid + 1280]);
  }
#pragma unroll
  for (int j = 0; j < 6; ++j) {
    const int c = tid + j * 256;
    float v = acc[j] + ob[c];
    v = fmaxf(v, 0.f);
    out[(size_t)i * ldc + c] = f2bf(v);
  }
}

// ---------------------------------------------------------------- final dot
__global__ __launch_bounds__(256)
void final_dot(const uint16_t* __restrict__ z2, const float* __restrict__ w,
               const float* __restrict__ b, float* __restrict__ out)
{
  const int row  = blockIdx.x * 4 + (threadIdx.x >> 6);
  const int lane = threadIdx.x & 63;
  const uint16_t* p = z2 + (size_t)row * 512;
  float s = 0.f;
#pragma unroll
  for (int j = 0; j < 8; ++j) { const int c = lane + j * 64; s += bf2f(p[c]) * w[c]; }
#pragma unroll
  for (int o = 32; o; o >>= 1) s += __shfl_xor(s, o);
  if (lane == 0) out[row] = s + b[0];
}

// ---------------------------------------------------------------- orchestration
extern "C" void kernel_launch(void* const* d_in, const int* in_sizes, int n_in,
                              void* d_out, int out_size, void* d_ws, size_t ws_size,
                              hipStream_t stream)
{
  (void)in_sizes; (void)n_in; (void)out_size; (void)ws_size;

  const float* x    = (const float*)d_in[0];
  const int*   ei   = (const int*)  d_in[1];
  const float* expm = (const float*)d_in[2];
  const float* w1l = (const float*)d_in[3];  const float* b1l = (const float*)d_in[4];
  const float* w1r = (const float*)d_in[5];  const float* b1r = (const float*)d_in[6];
  const float* a1  = (const float*)d_in[7];  const float* o1  = (const float*)d_in[8];
  const float* w2l = (const float*)d_in[9];  const float* b2l = (const float*)d_in[10];
  const float* w2r = (const float*)d_in[11]; const float* b2r = (const float*)d_in[12];
  const float* a2  = (const float*)d_in[13]; const float* o2  = (const float*)d_in[14];
  const float* w3l = (const float*)d_in[15]; const float* b3l = (const float*)d_in[16];
  const float* w3r = (const float*)d_in[17]; const float* b3r = (const float*)d_in[18];
  const float* a3  = (const float*)d_in[19]; const float* o3  = (const float*)d_in[20];
  const float* e1w = (const float*)d_in[21]; const float* e1b = (const float*)d_in[22];
  const float* e2w = (const float*)d_in[23]; const float* e2b = (const float*)d_in[24];
  const float* e3w = (const float*)d_in[25]; const float* e3b = (const float*)d_in[26];
  const float* l1w = (const float*)d_in[27]; const float* l1b = (const float*)d_in[28];
  const float* l2w = (const float*)d_in[29]; const float* l2b = (const float*)d_in[30];
  const float* l3w = (const float*)d_in[31]; const float* l3b = (const float*)d_in[32];
  float* out = (float*)d_out;

  hipFuncSetAttribute((const void*)gemm256, hipFuncAttributeMaxDynamicSharedMemorySize, 131072);

  char* ws = (char*)d_ws;
  size_t off = 0;
  auto take = [&](size_t b) { char* p = ws + off; off += (b + 255) & ~(size_t)255; return p; };

  int*      counts    = (int*)take((size_t)NN * 4);
  int*      row_start = (int*)take((size_t)(NN + 1) * 4);
  int*      cursor    = (int*)take((size_t)NN * 4);
  int*      csr_src   = (int*)take((size_t)ET * 4);
  int*      csr_dst   = (int*)take((size_t)ET * 4);
  float*    logits    = (float*)take((size_t)ET * 3 * 4);
  uint16_t* zbuf      = (uint16_t*)take((size_t)NN * 2048 * 2);
  char*     regA      = take((size_t)NN * F_EXP_P * 2);
  char*     regW      = take((size_t)4096 * F_EXP_P * 2);
  char*     regC      = take((size_t)NN * 4096 * 2 + (size_t)NN * 1536 * 2);

  const size_t HCB = (size_t)NN * 1536 * 2;
  uint16_t* xbf   = (uint16_t*)regA;
  uint16_t* expbf = (uint16_t*)regA;
  uint16_t* wT    = (uint16_t*)regW;
  uint16_t* xlb   = (uint16_t*)regC;
  uint16_t* xrb   = (uint16_t*)(regC + HCB);
  uint16_t* hbuf  = (uint16_t*)(regC + 2 * HCB);
  uint16_t* cell1 = (uint16_t*)regC;
  uint16_t* cell2 = (uint16_t*)(regC + (size_t)NN * 4096 * 2);
  uint16_t* zz1   = (uint16_t*)regC;
  uint16_t* zz2   = (uint16_t*)(regC + (size_t)NN * 1024 * 2);

  // ---- CSR
  hipMemsetAsync(counts, 0, (size_t)NN * 4, stream);
  count_deg<<<(ET + 255) / 256, 256, 0, stream>>>(ei, counts);
  scan_deg<<<1, 1024, 0, stream>>>(counts, row_start, cursor);
  scatter_e<<<(ET + 255) / 256, 256, 0, stream>>>(ei, cursor, csr_src, csr_dst);

  // ---- GAT layer 1 (Kp = 3264)
  cvt_pad<<<dim3((F_IN_P / 2 + 255) / 256, NN), 256, 0, stream>>>(x, xbf, F_IN, F_IN_P);
  transpose_w<<<dim3(F_IN_P / 32, 1536 / 32), dim3(32, 8), 0, stream>>>(w1l, wT, F_IN, 1536, F_IN_P, 1536);
  gemm256<<<32 * 6, 512, 131072, stream>>>(xbf, wT, b1l, 1536, 0, xlb, F_IN_P, 1536, 6);
  transpose_w<<<dim3(F_IN_P / 32, 1536 / 32), dim3(32, 8), 0, stream>>>(w1r, wT, F_IN, 1536, F_IN_P, 1536);
  gemm256<<<32 * 6, 512, 131072, stream>>>(xbf, wT, b1r, 1536, 0, xrb, F_IN_P, 1536, 6);
  gat_logits<<<ET / 4, 256, 0, stream>>>(xlb, xrb, csr_src, csr_dst, a1, logits);
  gat_aggregate<<<NN, 256, 0, stream>>>(logits, csr_src, row_start, xlb, o1, hbuf, 1536);

  // ---- GAT layer 2
  transpose_w<<<dim3(48, 48), dim3(32, 8), 0, stream>>>(w2l, wT, 1536, 1536, 1536, 1536);
  gemm256<<<32 * 6, 512, 131072, stream>>>(hbuf, wT, b2l, 1536, 0, xlb, 1536, 1536, 6);
  transpose_w<<<dim3(48, 48), dim3(32, 8), 0, stream>>>(w2r, wT, 1536, 1536, 1536, 1536);
  gemm256<<<32 * 6, 512, 131072, stream>>>(hbuf, wT, b2r, 1536, 0, xrb, 1536, 1536, 6);
  gat_logits<<<ET / 4, 256, 0, stream>>>(xlb, xrb, csr_src, csr_dst, a2, logits);
  gat_aggregate<<<NN, 256, 0, stream>>>(logits, csr_src, row_start, xlb, o2, hbuf, 1536);

  // ---- GAT layer 3 -> zbuf cols [0,1536)
  transpose_w<<<dim3(48, 48), dim3(32, 8), 0, stream>>>(w3l, wT, 1536, 1536, 1536, 1536);
  gemm256<<<32 * 6, 512, 131072, stream>>>(hbuf, wT, b3l, 1536, 0, xlb, 1536, 1536, 6);
  transpose_w<<<dim3(48, 48), dim3(32, 8), 0, stream>>>(w3r, wT, 1536, 1536, 1536, 1536);
  gemm256<<<32 * 6, 512, 131072, stream>>>(hbuf, wT, b3r, 1536, 0, xrb, 1536, 1536, 6);
  gat_logits<<<ET / 4, 256, 0, stream>>>(xlb, xrb, csr_src, csr_dst, a3, logits);
  gat_aggregate<<<NN, 256, 0, stream>>>(logits, csr_src, row_start, xlb, o3, zbuf, 2048);

  // ---- encoder: 7993 -> 4000 -> 1500 -> 512 (last into zbuf cols [1536,2048))
  cvt_pad<<<dim3((F_EXP_P / 2 + 255) / 256, NN), 256, 0, stream>>>(expm, expbf, F_EXP, F_EXP_P);
  transpose_w<<<dim3(F_EXP_P / 32, 4096 / 32), dim3(32, 8), 0, stream>>>(e1w, wT, F_EXP, 4000, F_EXP_P, 4096);
  gemm256<<<32 * 16, 512, 131072, stream>>>(expbf, wT, e1b, 4000, 1, cell1, F_EXP_P, 4096, 16);
  transpose_w<<<dim3(4096 / 32, 1536 / 32), dim3(32, 8), 0, stream>>>(e2w, wT, 4000, 1500, 4096, 1536);
  gemm256<<<32 * 6, 512, 131072, stream>>>(cell1, wT, e2b, 1500, 1, cell2, 4096, 1536, 6);
  transpose_w<<<dim3(1536 / 32, 512 / 32), dim3(32, 8), 0, stream>>>(e3w, wT, 1500, 512, 1536, 512);
  gemm_bt<<<dim3(64, 4), 256, 0, stream>>>(cell2, wT, e3b, 512, 0, zbuf + 1536, 1536, 2048);

  // ---- head
  transpose_w<<<dim3(2048 / 32, 1024 / 32), dim3(32, 8), 0, stream>>>(l1w, wT, 2048, 1024, 2048, 1024);
  gemm_bt<<<dim3(64, 8), 256, 0, stream>>>(zbuf, wT, l1b, 1024, 1, zz1, 2048, 1024);
  transpose_w<<<dim3(1024 / 32, 512 / 32), dim3(32, 8), 0, stream>>>(l2w, wT, 1024, 512, 1024, 512);
  gemm_bt<<<dim3(64, 4), 256, 0, stream>>>(zz1, wT, l2b, 512, 1, zz2, 1024, 512);
  final_dot<<<NN / 4, 256, 0, stream>>>(zz2, l3w, l3b, out);
}